// Round 7
// baseline (348.201 us; speedup 1.0000x reference)
//
#include <hip/hip_runtime.h>
#include <hip/hip_cooperative_groups.h>
#include <math.h>

namespace cg = cooperative_groups;

#define N_ 2048
#define D_ 1024
#define TOPK 10
#define TOPK_HALF 5
#define NTRI 528
#define INV_NORM (1.0f / ((float)N_ * (float)(N_ - 1)))

typedef __attribute__((ext_vector_type(8))) short short8;
typedef __attribute__((ext_vector_type(4))) float floatx4;

__device__ __forceinline__ short f2bf(float f) {
  unsigned u = __float_as_uint(f);
  unsigned r = (u + 0x7fffu + ((u >> 16) & 1u)) >> 16;
  return (short)r;
}
__device__ __forceinline__ float bf2f(short b) {
  return __uint_as_float(((unsigned)(unsigned short)b) << 16);
}

__device__ __forceinline__ void gld_lds16(const short* g, short* l) {
  __builtin_amdgcn_global_load_lds(
      (const __attribute__((address_space(1))) unsigned int*)(g),
      (__attribute__((address_space(3))) unsigned int*)(l), 16, 0, 0);
}

#define BAR() asm volatile("s_barrier" ::: "memory")
#define WAIT4_BAR() asm volatile("s_waitcnt vmcnt(4)\ns_barrier" ::: "memory")
#define WAIT0_BAR() asm volatile("s_waitcnt vmcnt(0)\ns_barrier" ::: "memory")

__global__ __launch_bounds__(256, 4) void mega_kernel(
    const float* __restrict__ t, const float* __restrict__ s,
    short* __restrict__ tb, short* __restrict__ sb,
    float* __restrict__ tt, float* __restrict__ ss,
    float* __restrict__ rowsum, int* __restrict__ idx,
    unsigned* __restrict__ mask,
    short* __restrict__ WPb, short* __restrict__ Sob,
    float* __restrict__ out) {
  cg::grid_group grid = cg::this_grid();
  __shared__ __align__(16) short smem[4 * 4096];  // 32 KB: gram dbuf / reductions
  int tid = threadIdx.x, w = tid >> 6, lane = tid & 63;

  // ================= Phase A: prep (wave-per-row, shuffle-only) =================
  if (blockIdx.x == 0) {
    for (int j = tid; j < N_; j += 256) rowsum[j] = 0.f;
    if (tid == 0) out[0] = 0.f;
  }
  if (blockIdx.x == 1 % gridDim.x) {
    for (int j = tid; j < N_; j += 256) mask[j] = 0u;
  }
  for (int row = blockIdx.x * 4 + w; row < 2 * N_; row += gridDim.x * 4) {
    if (row < N_) {  // t-norm
      const float4* rp = (const float4*)(t + (size_t)row * D_);
      float4 v[4];
      float acc = 0.f;
#pragma unroll
      for (int c4 = 0; c4 < 4; c4++) {
        v[c4] = rp[lane + 64 * c4];
        acc += v[c4].x * v[c4].x + v[c4].y * v[c4].y + v[c4].z * v[c4].z + v[c4].w * v[c4].w;
      }
#pragma unroll
      for (int off = 1; off < 64; off <<= 1) acc += __shfl_xor(acc, off);
      float inv = 1.f / fmaxf(sqrtf(acc), 1e-12f);
      float s2 = 0.f;
#pragma unroll
      for (int c4 = 0; c4 < 4; c4++) {
        float a = v[c4].x * inv, b = v[c4].y * inv, c = v[c4].z * inv, d = v[c4].w * inv;
        uint2 pk;
        pk.x = (unsigned)(unsigned short)f2bf(a) | ((unsigned)(unsigned short)f2bf(b) << 16);
        pk.y = (unsigned)(unsigned short)f2bf(c) | ((unsigned)(unsigned short)f2bf(d) << 16);
        ((uint2*)(tb + (size_t)row * D_))[lane + 64 * c4] = pk;
        s2 += a * a + b * b + c * c + d * d;
      }
#pragma unroll
      for (int off = 1; off < 64; off <<= 1) s2 += __shfl_xor(s2, off);
      if (lane == 0) tt[row] = s2;
    } else {  // s-conv
      int r2 = row - N_;
      const float4* rp = (const float4*)(s + (size_t)r2 * D_);
      float acc = 0.f;
#pragma unroll
      for (int c4 = 0; c4 < 4; c4++) {
        float4 v = rp[lane + 64 * c4];
        uint2 pk;
        pk.x = (unsigned)(unsigned short)f2bf(v.x) | ((unsigned)(unsigned short)f2bf(v.y) << 16);
        pk.y = (unsigned)(unsigned short)f2bf(v.z) | ((unsigned)(unsigned short)f2bf(v.w) << 16);
        ((uint2*)(sb + (size_t)r2 * D_))[lane + 64 * c4] = pk;
        acc += v.x * v.x + v.y * v.y + v.z * v.z + v.w * v.w;
      }
#pragma unroll
      for (int off = 1; off < 64; off <<= 1) acc += __shfl_xor(acc, off);
      if (lane == 0) ss[r2] = acc;
    }
  }
  grid.sync();

  // ================= Phase C: symmetric gram (triangle 64x64 tiles) =================
  for (int p = blockIdx.x; p < 2 * NTRI; p += gridDim.x) {
    __syncthreads();  // LDS reuse across tasks
    const int mode = (p >= NTRI);
    int q = p - mode * NTRI;
    int bi = (int)((sqrtf(8.f * (float)q + 1.f) - 1.f) * 0.5f);
    if (bi > 31) bi = 31;
    while ((bi + 1) * (bi + 2) / 2 <= q) bi++;
    while (bi * (bi + 1) / 2 > q) bi--;
    int bj = q - bi * (bi + 1) / 2;

    const short* A = mode ? sb : tb;
    const float* rn = mode ? ss : tt;
    short* outb = mode ? Sob : WPb;

    int i0 = bi * 64, j0 = bj * 64;
    int wr = w >> 1, wc = w & 1;
    int quad = lane >> 4, l16 = lane & 15;
    floatx4 acc[2][2] = {};

    int sr8 = lane >> 3;
    int gch = ((lane & 7) ^ sr8) * 8;
    const short* Ag = A + (size_t)(i0 + w * 16 + sr8) * D_ + gch;
    const short* Bg = A + (size_t)(j0 + w * 16 + sr8) * D_ + gch;
    int lloc = (w * 16 + sr8) * 64 + (lane & 7) * 8;

#define STAGE(buf, k0)                                       \
  do {                                                       \
    short* Al = smem + (buf)*8192 + lloc;                    \
    short* Bl = smem + (buf)*8192 + 4096 + lloc;             \
    gld_lds16(Ag + (k0), Al);                                \
    gld_lds16(Ag + (k0) + (size_t)8 * D_, Al + 512);         \
    gld_lds16(Bg + (k0), Bl);                                \
    gld_lds16(Bg + (k0) + (size_t)8 * D_, Bl + 512);         \
  } while (0)

    STAGE(0, 0);
#pragma unroll 2
    for (int it = 0; it < 16; it++) {
      int cur = it & 1;
      if (it) BAR();
      if (it < 15) {
        STAGE(!cur, (it + 1) * 64);
        WAIT4_BAR();
      } else {
        WAIT0_BAR();
      }
      const short* Ab = smem + cur * 8192;
      const short* Bb = smem + cur * 8192 + 4096;
#pragma unroll
      for (int ks = 0; ks < 64; ks += 32) {
        int cb = ks >> 3;
        short8 af[2], bfr[2];
#pragma unroll
        for (int mt = 0; mt < 2; mt++) {
          int rr = wr * 32 + mt * 16 + l16;
          af[mt] = *(const short8*)&Ab[rr * 64 + (((cb + quad) ^ (l16 & 7)) << 3)];
        }
#pragma unroll
        for (int nt = 0; nt < 2; nt++) {
          int rr = wc * 32 + nt * 16 + l16;
          bfr[nt] = *(const short8*)&Bb[rr * 64 + (((cb + quad) ^ (l16 & 7)) << 3)];
        }
#pragma unroll
        for (int mt = 0; mt < 2; mt++)
#pragma unroll
          for (int nt = 0; nt < 2; nt++)
            acc[mt][nt] = __builtin_amdgcn_mfma_f32_16x16x32_bf16(af[mt], bfr[nt], acc[mt][nt], 0, 0, 0);
      }
    }

    float ov[2][2][4];
#pragma unroll
    for (int mt = 0; mt < 2; mt++) {
#pragma unroll
      for (int r = 0; r < 4; r++) {
        int i = i0 + wr * 32 + mt * 16 + quad * 4 + r;
        float ri = rn[i];
        float rs = 0.f;
#pragma unroll
        for (int nt = 0; nt < 2; nt++) {
          int j = j0 + wc * 32 + nt * 16 + l16;
          float d2 = fmaxf(ri + rn[j] - 2.f * acc[mt][nt][r], 0.f);
          float o = mode ? sqrtf(d2) : expf(-d2);
          if (i == j) o = mode ? 0.f : 1.f;
          ov[mt][nt][r] = o;
          outb[(size_t)i * N_ + j] = f2bf(o);
          rs += o;
        }
        if (mode) {
          rs += __shfl_xor(rs, 1); rs += __shfl_xor(rs, 2);
          rs += __shfl_xor(rs, 4); rs += __shfl_xor(rs, 8);
          if (l16 == 0) atomicAdd(&rowsum[i], rs);
        }
      }
    }

    if (bi != bj) {
      if (mode) {
#pragma unroll
        for (int nt = 0; nt < 2; nt++) {
          float cs = 0.f;
#pragma unroll
          for (int mt = 0; mt < 2; mt++)
#pragma unroll
            for (int r = 0; r < 4; r++) cs += ov[mt][nt][r];
          cs += __shfl_xor(cs, 16);
          cs += __shfl_xor(cs, 32);
          if (quad == 0) atomicAdd(&rowsum[j0 + wc * 32 + nt * 16 + l16], cs);
        }
      }
      BAR();  // K-loop slab reads done before scratch overwrite
      float* fs = (float*)smem + w * 1088;
#pragma unroll
      for (int mt = 0; mt < 2; mt++)
#pragma unroll
        for (int nt = 0; nt < 2; nt++)
#pragma unroll
          for (int r = 0; r < 4; r++)
            fs[(nt * 16 + l16) * 34 + mt * 16 + quad * 4 + r] = ov[mt][nt][r];
#pragma unroll
      for (int itx = 0; itx < 8; itx++) {
        int sidx = itx * 64 + lane;
        int lc = sidx >> 4;
        int k2 = (sidx & 15) * 2;
        float lo = fs[lc * 34 + k2];
        float hi = fs[lc * 34 + k2 + 1];
        unsigned pk = (unsigned)(unsigned short)f2bf(lo) |
                      ((unsigned)(unsigned short)f2bf(hi) << 16);
        size_t jg = (size_t)(j0 + wc * 32 + lc);
        *(unsigned*)(outb + jg * N_ + i0 + wr * 32 + k2) = pk;
      }
    }
  }
  grid.sync();

  // ================= Phase E: wave-per-row dense loss + top-10 =================
  if (w < 2) {
    for (int row = blockIdx.x * 2 + w; row < N_; row += gridDim.x * 2) {
      const short8* wpr = (const short8*)(WPb + (size_t)row * N_);
      const short8* sr = (const short8*)(Sob + (size_t)row * N_);
      float rminv = (float)N_ / rowsum[row];
      float wreg[32];
      float local = 0.f;
#pragma unroll
      for (int c4 = 0; c4 < 4; c4++) {
        short8 wp8 = wpr[lane * 4 + c4];
        short8 s8 = sr[lane * 4 + c4];
#pragma unroll
        for (int e = 0; e < 8; e++) {
          float wv = bf2f(wp8[e]);
          wreg[c4 * 8 + e] = wv;
          float sv = bf2f(s8[e]) * rminv;
          float d = fmaxf(1.f - sv, 0.f);
          local += d * d + 0.5f * wv * (sv * sv - d * d);
        }
      }
#pragma unroll
      for (int off = 32; off > 0; off >>= 1) local += __shfl_down(local, off);
      if (lane == 0) atomicAdd(out, (local - 0.5f) * INV_NORM);
      int base = lane * 32;
      int sel[TOPK];
      for (int tq = 0; tq < TOPK; tq++) {
        float bv = -2.f; int bi = 0;
#pragma unroll
        for (int c = 0; c < 32; c++)
          if (wreg[c] > bv) { bv = wreg[c]; bi = base + c; }
#pragma unroll
        for (int off = 32; off > 0; off >>= 1) {
          float ovv = __shfl_down(bv, off);
          int oi = __shfl_down(bi, off);
          if (ovv > bv || (ovv == bv && oi < bi)) { bv = ovv; bi = oi; }
        }
        bi = __shfl(bi, 0);
        sel[tq] = bi;
        bool mine = (bi >> 5) == lane;
        int cc = bi & 31;
#pragma unroll
        for (int c = 0; c < 32; c++)
          if (mine && cc == c) wreg[c] = -1.f;
      }
      if (lane == 0) {
#pragma unroll
        for (int tq = 0; tq < TOPK; tq++) idx[row * TOPK + tq] = sel[tq];
      }
    }
  }
  grid.sync();

  // ================= Phase F: mutual kNN bitmask =================
  for (int tk = blockIdx.x * 256 + tid; tk < N_ * 16; tk += gridDim.x * 256) {
    int i = tk >> 4, k = tk & 15;
    if (k < TOPK) {
      int j = idx[i * TOPK + k];
      bool mut = false;
#pragma unroll
      for (int l = 0; l < TOPK; l++) mut |= (idx[j * TOPK + l] == i);
      if (mut) atomicOr(&mask[i], 1u << k);
    }
  }
  grid.sync();

  // ================= Phase G: sparse W_C contribution =================
  float contrib = 0.f;
  for (int tk = blockIdx.x * 256 + tid; tk < N_ * 64; tk += gridDim.x * 256) {
    int i = tk >> 6, r = tk & 63;
    if (r < TOPK_HALF * TOPK) {
      int mi = r / TOPK, k = r - mi * TOPK;
      int m = idx[i * TOPK + mi];
      unsigned mm = mask[m];
      if ((mm >> k) & 1u) {
        int col = idx[m * TOPK + k];
        if (col != i) {
          int dm = __popc(mm);
          unsigned mc = mask[col];
          int jm[TOPK], jc[TOPK];
#pragma unroll
          for (int l = 0; l < TOPK; l++) jm[l] = idx[m * TOPK + l];
#pragma unroll
          for (int l = 0; l < TOPK; l++) jc[l] = idx[col * TOPK + l];
          int c = 0;
#pragma unroll
          for (int a = 0; a < TOPK; a++) {
            if ((mm >> a) & 1u) {
              int na = jm[a];
#pragma unroll
              for (int b = 0; b < TOPK; b++) c += (((mc >> b) & 1u) && (jc[b] == na));
            }
          }
          float v = (float)c / (float)dm * 0.1f;
          float s1 = bf2f(Sob[(size_t)i * N_ + col]) * ((float)N_ / rowsum[i]);
          float d1 = fmaxf(1.f - s1, 0.f);
          float s2 = bf2f(Sob[(size_t)col * N_ + i]) * ((float)N_ / rowsum[col]);
          float d2 = fmaxf(1.f - s2, 0.f);
          contrib += 0.5f * v * ((s1 * s1 - d1 * d1) + (s2 * s2 - d2 * d2));
        }
      }
    }
  }
  __syncthreads();
  float* red = (float*)smem;
  red[tid] = contrib;
  __syncthreads();
  for (int st = 128; st > 0; st >>= 1) {
    if (tid < st) red[tid] += red[tid + st];
    __syncthreads();
  }
  if (tid == 0) atomicAdd(out, red[0] * INV_NORM);
}

extern "C" void kernel_launch(void* const* d_in, const int* in_sizes, int n_in,
                              void* d_out, int out_size, void* d_ws, size_t ws_size,
                              hipStream_t stream) {
  const float* s_emb = (const float*)d_in[0];
  const float* t_emb = (const float*)d_in[1];
  float* out = (float*)d_out;

  const size_t NN = (size_t)N_ * N_;
  const size_t ND = (size_t)N_ * D_;
  short* t_bf = (short*)d_ws;                        // N*D bf16
  short* s_bf = t_bf + ND;                           // N*D bf16
  short* WPb = s_bf + ND;                            // N*N bf16
  short* Sb = WPb + NN;                              // N*N bf16
  float* tt = (float*)(Sb + NN);                     // N
  float* ss = tt + N_;                               // N
  float* rowsum = ss + N_;                           // N
  int* idx = (int*)(rowsum + N_);                    // N*TOPK
  unsigned* mask = (unsigned*)(idx + (size_t)N_ * TOPK);  // N

  int nb = 4;
  hipOccupancyMaxActiveBlocksPerMultiprocessor(&nb, mega_kernel, 256, 0);
  int grid = nb * 256;
  if (grid > 1024) grid = 1024;
  if (grid < 256) grid = 256;  // 4096 wave-rows need >= 1024 waves? stride loops handle any >=1

  void* args[] = {(void*)&t_emb, (void*)&s_emb, (void*)&t_bf, (void*)&s_bf,
                  (void*)&tt,    (void*)&ss,    (void*)&rowsum, (void*)&idx,
                  (void*)&mask,  (void*)&WPb,   (void*)&Sb,     (void*)&out};
  hipLaunchCooperativeKernel((void*)mega_kernel, dim3(grid), dim3(256), args, 0, stream);
}

// Round 8
// 151.156 us; speedup vs baseline: 2.3036x; 2.3036x over previous
//
#include <hip/hip_runtime.h>
#include <math.h>

#define N_ 2048
#define D_ 1024
#define TOPK 10
#define TOPK_HALF 5
#define NTRI 528
#define INV_NORM (1.0f / ((float)N_ * (float)(N_ - 1)))

typedef __attribute__((ext_vector_type(8))) short short8;
typedef __attribute__((ext_vector_type(16))) float floatx16;

__device__ __forceinline__ short f2bf(float f) {
  unsigned u = __float_as_uint(f);
  unsigned r = (u + 0x7fffu + ((u >> 16) & 1u)) >> 16;
  return (short)r;
}
__device__ __forceinline__ float bf2f(short b) {
  return __uint_as_float(((unsigned)(unsigned short)b) << 16);
}

__device__ __forceinline__ void gld_lds16(const short* g, short* l) {
  __builtin_amdgcn_global_load_lds(
      (const __attribute__((address_space(1))) unsigned int*)(g),
      (__attribute__((address_space(3))) unsigned int*)(l), 16, 0, 0);
}

#define BAR() asm volatile("s_barrier" ::: "memory")
#define WAIT4_BAR() asm volatile("s_waitcnt vmcnt(4)\ns_barrier" ::: "memory")
#define WAIT0_BAR() asm volatile("s_waitcnt vmcnt(0)\ns_barrier" ::: "memory")

// ---------- prep: normalize t -> bf16 (+tt), convert s -> bf16 (+ss); zero rowsum & out ----------
__global__ __launch_bounds__(256) void prep_kernel(const float* __restrict__ t,
                                                   const float* __restrict__ s,
                                                   short* __restrict__ tb,
                                                   short* __restrict__ sb,
                                                   float* __restrict__ tt,
                                                   float* __restrict__ ss,
                                                   float* __restrict__ rowsum,
                                                   float* __restrict__ out) {
  int b = blockIdx.x, tid = threadIdx.x;
  __shared__ float red[256];
  if (b == 0) {
    for (int j = tid; j < N_; j += 256) rowsum[j] = 0.f;
    if (tid == 0) out[0] = 0.f;
  }
  if (b < N_) {  // tnorm row b
    const float4* rp = (const float4*)(t + (size_t)b * D_);
    float4 v = rp[tid];
    red[tid] = v.x * v.x + v.y * v.y + v.z * v.z + v.w * v.w;
    __syncthreads();
    for (int st = 128; st > 0; st >>= 1) { if (tid < st) red[tid] += red[tid + st]; __syncthreads(); }
    float inv = 1.f / fmaxf(sqrtf(red[0]), 1e-12f);
    __syncthreads();
    float a = v.x * inv, bb = v.y * inv, c = v.z * inv, d = v.w * inv;
    uint2 pk;
    pk.x = (unsigned)(unsigned short)f2bf(a) | ((unsigned)(unsigned short)f2bf(bb) << 16);
    pk.y = (unsigned)(unsigned short)f2bf(c) | ((unsigned)(unsigned short)f2bf(d) << 16);
    ((uint2*)(tb + (size_t)b * D_))[tid] = pk;
    red[tid] = a * a + bb * bb + c * c + d * d;
    __syncthreads();
    for (int st = 128; st > 0; st >>= 1) { if (tid < st) red[tid] += red[tid + st]; __syncthreads(); }
    if (tid == 0) tt[b] = red[0];
  } else {  // sconv row b-N_
    int row = b - N_;
    const float4* rp = (const float4*)(s + (size_t)row * D_);
    float4 v = rp[tid];
    uint2 pk;
    pk.x = (unsigned)(unsigned short)f2bf(v.x) | ((unsigned)(unsigned short)f2bf(v.y) << 16);
    pk.y = (unsigned)(unsigned short)f2bf(v.z) | ((unsigned)(unsigned short)f2bf(v.w) << 16);
    ((uint2*)(sb + (size_t)row * D_))[tid] = pk;
    red[tid] = v.x * v.x + v.y * v.y + v.z * v.z + v.w * v.w;
    __syncthreads();
    for (int st = 128; st > 0; st >>= 1) { if (tid < st) red[tid] += red[tid + st]; __syncthreads(); }
    if (tid == 0) ss[row] = red[0];
  }
}

// ---------- symmetric bf16-MFMA Gram: lower-triangle 64x64 blocks, dbuf LDS, 32x32x16 ----------
__global__ __launch_bounds__(256) void gram_sym_kernel(
    const short* __restrict__ Tb, const short* __restrict__ Sb,
    const float* __restrict__ tt, const float* __restrict__ ss,
    short* __restrict__ WPb, short* __restrict__ Sob,
    float* __restrict__ rowsum) {
  int p = blockIdx.x;
  const int mode = (p >= NTRI);
  int q = p - mode * NTRI;
  int bi = (int)((sqrtf(8.f * (float)q + 1.f) - 1.f) * 0.5f);
  if (bi > 31) bi = 31;
  while ((bi + 1) * (bi + 2) / 2 <= q) bi++;
  while (bi * (bi + 1) / 2 > q) bi--;
  int bj = q - bi * (bi + 1) / 2;  // 0 <= bj <= bi

  const short* A = mode ? Sb : Tb;
  const float* rn = mode ? ss : tt;
  short* outb = mode ? Sob : WPb;

  __shared__ __align__(16) short smem[4 * 4096];  // dbuf: [buf][A|B] 64x64 slabs

  int tid = threadIdx.x;
  int w = tid >> 6, lane = tid & 63;
  int i0 = bi * 64, j0 = bj * 64;
  int wr = w >> 1, wc = w & 1;
  int l32 = lane & 31, half = lane >> 5;

  floatx16 acc = {};

  // staging: wave w stages rows [w*16, w*16+16), XOR chunk swizzle
  int sr8 = lane >> 3;
  int gch = ((lane & 7) ^ sr8) * 8;
  const short* Ag = A + (size_t)(i0 + w * 16 + sr8) * D_ + gch;
  const short* Bg = A + (size_t)(j0 + w * 16 + sr8) * D_ + gch;
  int lloc = (w * 16 + sr8) * 64 + (lane & 7) * 8;

#define STAGE(buf, k0)                                       \
  do {                                                       \
    short* Al = smem + (buf)*8192 + lloc;                    \
    short* Bl = smem + (buf)*8192 + 4096 + lloc;             \
    gld_lds16(Ag + (k0), Al);                                \
    gld_lds16(Ag + (k0) + (size_t)8 * D_, Al + 512);         \
    gld_lds16(Bg + (k0), Bl);                                \
    gld_lds16(Bg + (k0) + (size_t)8 * D_, Bl + 512);         \
  } while (0)

  STAGE(0, 0);
#pragma unroll 2
  for (int it = 0; it < 16; it++) {
    int cur = it & 1;
    if (it) BAR();
    if (it < 15) {
      STAGE(!cur, (it + 1) * 64);
      WAIT4_BAR();
    } else {
      WAIT0_BAR();
    }
    const short* Ab = smem + cur * 8192;
    const short* Bb = smem + cur * 8192 + 4096;
#pragma unroll
    for (int kstep = 0; kstep < 4; kstep++) {
      int cA = (((2 * kstep + half) ^ (l32 & 7)) << 3);
      short8 af = *(const short8*)&Ab[(wr * 32 + l32) * 64 + cA];
      short8 bfr = *(const short8*)&Bb[(wc * 32 + l32) * 64 + cA];
      acc = __builtin_amdgcn_mfma_f32_32x32x16_bf16(af, bfr, acc, 0, 0, 0);
    }
  }

  // ---- epilogue: activate, direct store, row sums; then transposed tile ----
  // C/D: col = l32, row_local = (reg&3) + 8*(reg>>2) + 4*half
  float ov[16];
  int jcol = j0 + wc * 32 + l32;
  float rj = rn[jcol];
#pragma unroll
  for (int reg = 0; reg < 16; reg++) {
    int rl = (reg & 3) + 8 * (reg >> 2) + 4 * half;
    int i = i0 + wr * 32 + rl;
    float d2 = fmaxf(rn[i] + rj - 2.f * acc[reg], 0.f);
    float o = mode ? sqrtf(d2) : expf(-d2);
    if (i == jcol) o = mode ? 0.f : 1.f;
    ov[reg] = o;
    outb[(size_t)i * N_ + jcol] = f2bf(o);
  }
  if (mode) {
#pragma unroll
    for (int reg = 0; reg < 16; reg++) {
      float rs = ov[reg];
      rs += __shfl_xor(rs, 1); rs += __shfl_xor(rs, 2);
      rs += __shfl_xor(rs, 4); rs += __shfl_xor(rs, 8);
      rs += __shfl_xor(rs, 16);
      if (l32 == 0) {
        int rl = (reg & 3) + 8 * (reg >> 2) + 4 * half;
        atomicAdd(&rowsum[i0 + wr * 32 + rl], rs);
      }
    }
  }

  if (bi != bj) {
    if (mode) {
      float cs = 0.f;
#pragma unroll
      for (int reg = 0; reg < 16; reg++) cs += ov[reg];
      cs += __shfl_xor(cs, 32);
      if (half == 0) atomicAdd(&rowsum[jcol], cs);
    }
    BAR();  // K-loop slab reads done before scratch overwrite
    float* fs = (float*)smem + w * 1088;  // 32x32 fp32, pad 34, per wave
#pragma unroll
    for (int reg = 0; reg < 16; reg++) {
      int rl = (reg & 3) + 8 * (reg >> 2) + 4 * half;
      fs[l32 * 34 + rl] = ov[reg];
    }
#pragma unroll
    for (int itx = 0; itx < 8; itx++) {
      int sidx = itx * 64 + lane;
      int lc = sidx >> 4;        // transposed row (= original col)
      int k2 = (sidx & 15) * 2;  // original-row pair
      float lo = fs[lc * 34 + k2];
      float hi = fs[lc * 34 + k2 + 1];
      unsigned pk = (unsigned)(unsigned short)f2bf(lo) |
                    ((unsigned)(unsigned short)f2bf(hi) << 16);
      size_t jg = (size_t)(j0 + wc * 32 + lc);
      *(unsigned*)(outb + jg * N_ + i0 + wr * 32 + k2) = pk;
    }
  }
}

// ---------- wave-per-row: dense loss partial + register-resident top-10 ----------
__global__ __launch_bounds__(64) void topk_loss_kernel(const short* __restrict__ WPb,
                                                       const short* __restrict__ Sb,
                                                       const float* __restrict__ rowsum,
                                                       int* __restrict__ idx,
                                                       float* __restrict__ out) {
  int row = blockIdx.x, lane = threadIdx.x;
  const short8* wpr = (const short8*)(WPb + (size_t)row * N_);
  const short8* sr = (const short8*)(Sb + (size_t)row * N_);
  float rminv = (float)N_ / rowsum[row];
  float w[32];
  float local = 0.f;
#pragma unroll
  for (int c4 = 0; c4 < 4; c4++) {
    short8 wp8 = wpr[lane * 4 + c4];
    short8 s8 = sr[lane * 4 + c4];
#pragma unroll
    for (int e = 0; e < 8; e++) {
      float wv = bf2f(wp8[e]);
      w[c4 * 8 + e] = wv;
      float sv = bf2f(s8[e]) * rminv;
      float d = fmaxf(1.f - sv, 0.f);
      local += d * d + 0.5f * wv * (sv * sv - d * d);
    }
  }
#pragma unroll
  for (int off = 32; off > 0; off >>= 1) local += __shfl_down(local, off);
  if (lane == 0) atomicAdd(out, (local - 0.5f) * INV_NORM);  // subtract diag term
  int base = lane * 32;
  int sel[TOPK];
  for (int t = 0; t < TOPK; t++) {
    float bv = -2.f; int bi = 0;
#pragma unroll
    for (int c = 0; c < 32; c++)
      if (w[c] > bv) { bv = w[c]; bi = base + c; }
#pragma unroll
    for (int off = 32; off > 0; off >>= 1) {
      float ovv = __shfl_down(bv, off);
      int oi = __shfl_down(bi, off);
      if (ovv > bv || (ovv == bv && oi < bi)) { bv = ovv; bi = oi; }
    }
    bi = __shfl(bi, 0);
    sel[t] = bi;
    bool mine = (bi >> 5) == lane;
    int cc = bi & 31;
#pragma unroll
    for (int c = 0; c < 32; c++)
      if (mine && cc == c) w[c] = -1.f;
  }
  if (lane == 0) {
#pragma unroll
    for (int t = 0; t < TOPK; t++) idx[row * TOPK + t] = sel[t];
  }
}

// ---------- mutual mask for row x, recomputed inline ----------
__device__ __forceinline__ unsigned mutual_mask(const int* __restrict__ idx, int x) {
  unsigned m = 0;
  int nb[TOPK];
#pragma unroll
  for (int k = 0; k < TOPK; k++) nb[k] = idx[x * TOPK + k];
#pragma unroll
  for (int k = 0; k < TOPK; k++) {
    int j = nb[k];
    bool mut = false;
#pragma unroll
    for (int l = 0; l < TOPK; l++) mut |= (idx[j * TOPK + l] == x);
    if (mut) m |= 1u << k;
  }
  return m;
}

// ---------- sparse W_C part: one thread per (i, mi, k); mutual computed inline ----------
__global__ __launch_bounds__(256) void sparse_wc_kernel(
    const int* __restrict__ idx, const short* __restrict__ Sb,
    const float* __restrict__ rowsum, float* __restrict__ out) {
  int t = blockIdx.x * 256 + threadIdx.x;
  int i = t >> 6, r = t & 63;
  float contrib = 0.f;
  if (i < N_ && r < TOPK_HALF * TOPK) {
    int mi = r / TOPK, k = r - mi * TOPK;
    int m = idx[i * TOPK + mi];
    unsigned mm = mutual_mask(idx, m);
    if ((mm >> k) & 1u) {
      int col = idx[m * TOPK + k];
      if (col != i) {
        int dm = __popc(mm);
        unsigned mc = mutual_mask(idx, col);
        int jm[TOPK], jc[TOPK];
#pragma unroll
        for (int l = 0; l < TOPK; l++) jm[l] = idx[m * TOPK + l];
#pragma unroll
        for (int l = 0; l < TOPK; l++) jc[l] = idx[col * TOPK + l];
        int c = 0;
#pragma unroll
        for (int a = 0; a < TOPK; a++) {
          if ((mm >> a) & 1u) {
            int na = jm[a];
#pragma unroll
            for (int b = 0; b < TOPK; b++) c += (((mc >> b) & 1u) && (jc[b] == na));
          }
        }
        float v = (float)c / (float)dm * 0.1f;  // (1/5 mean) * (1/2 symmetrize)
        float s1 = bf2f(Sb[(size_t)i * N_ + col]) * ((float)N_ / rowsum[i]);
        float d1 = fmaxf(1.f - s1, 0.f);
        float s2 = bf2f(Sb[(size_t)col * N_ + i]) * ((float)N_ / rowsum[col]);
        float d2 = fmaxf(1.f - s2, 0.f);
        contrib = 0.5f * v * ((s1 * s1 - d1 * d1) + (s2 * s2 - d2 * d2));
      }
    }
  }
  __shared__ float red[256];
  red[threadIdx.x] = contrib; __syncthreads();
  for (int st = 128; st > 0; st >>= 1) {
    if (threadIdx.x < st) red[threadIdx.x] += red[threadIdx.x + st];
    __syncthreads();
  }
  if (threadIdx.x == 0) atomicAdd(out, red[0] * INV_NORM);
}

extern "C" void kernel_launch(void* const* d_in, const int* in_sizes, int n_in,
                              void* d_out, int out_size, void* d_ws, size_t ws_size,
                              hipStream_t stream) {
  const float* s_emb = (const float*)d_in[0];
  const float* t_emb = (const float*)d_in[1];
  float* out = (float*)d_out;

  const size_t NN = (size_t)N_ * N_;
  const size_t ND = (size_t)N_ * D_;
  short* t_bf = (short*)d_ws;                        // N*D bf16
  short* s_bf = t_bf + ND;                           // N*D bf16
  short* WPb = s_bf + ND;                            // N*N bf16
  short* Sb = WPb + NN;                              // N*N bf16
  float* tt = (float*)(Sb + NN);                     // N
  float* ss = tt + N_;                               // N
  float* rowsum = ss + N_;                           // N
  int* idx = (int*)(rowsum + N_);                    // N*TOPK

  prep_kernel<<<2 * N_, 256, 0, stream>>>(t_emb, s_emb, t_bf, s_bf, tt, ss, rowsum, out);

  gram_sym_kernel<<<2 * NTRI, 256, 0, stream>>>(t_bf, s_bf, tt, ss, WPb, Sb, rowsum);

  topk_loss_kernel<<<N_, 64, 0, stream>>>(WPb, Sb, rowsum, idx, out);
  sparse_wc_kernel<<<N_ * 64 / 256, 256, 0, stream>>>(idx, Sb, rowsum, out);
}